// Round 5
// baseline (3949.266 us; speedup 1.0000x reference)
//
#include <hip/hip_runtime.h>
#include <math.h>

// ---------------------------------------------------------------------------
// VQ-VAE forward. Round 4 (resubmit after acquisition timeout):
//  - convt1/convt2 rewritten: x rows staged in LDS, weights from L2
//    (wave-uniform broadcasts / lane-coalesced), phase math identical to the
//    validated round-2 kernels.
//  - whole 5x6-spatial chain (enc3, res x2, pre, VQ, dec1, res x2, relu+pad)
//    fused into one kernel, activations LDS-resident.
// ---------------------------------------------------------------------------

// conv1: x(32,2,400,600) w(64,2,10,11) s(8,9) p(1,1) -> y(32,64,50,66), +b, relu
__global__ __launch_bounds__(256) void conv1_k(const float* __restrict__ x,
                                               const float* __restrict__ w,
                                               const float* __restrict__ b,
                                               float* __restrict__ y)
{
    __shared__ float xs[2 * 10 * 596]; // 47.68 KB
    const int blk = blockIdx.x;            // 32*50 = 1600
    const int n = blk / 50, oh = blk % 50;
    const int tid = threadIdx.x;
    const int ih0 = oh * 8 - 1;
    for (int i = tid; i < 2 * 10 * 596; i += 256) {
        int c = i / 5960, rem = i % 5960;
        int r = rem / 596, j = rem % 596;
        int ih = ih0 + r, iw = j - 1;
        float v = 0.f;
        if (ih >= 0 && ih < 400 && iw >= 0 && iw < 600)
            v = x[((n * 2 + c) * 400 + ih) * 600 + iw];
        xs[i] = v;
    }
    __syncthreads();
    for (int i = tid; i < 32 * 66; i += 256) {
        int oc = i / 66, ow = i % 66;
        int col = ow * 9;
        float a0 = 0.f, a1 = 0.f;
        for (int c = 0; c < 2; ++c) {
            const float* wp0 = w + ((oc)      * 2 + c) * 110;
            const float* wp1 = w + ((oc + 32) * 2 + c) * 110;
            const float* xp  = xs + c * 5960 + col;
            for (int kh = 0; kh < 10; ++kh) {
                #pragma unroll
                for (int kw = 0; kw < 11; ++kw) {
                    float xv = xp[kh * 596 + kw];
                    a0 += xv * wp0[kh * 11 + kw];
                    a1 += xv * wp1[kh * 11 + kw];
                }
            }
        }
        y[((n * 64 + oc)      * 50 + oh) * 66 + ow] = fmaxf(a0 + b[oc], 0.f);
        y[((n * 64 + oc + 32) * 50 + oh) * 66 + ow] = fmaxf(a1 + b[oc + 32], 0.f);
    }
}

// repack OIHW -> [c][kh][kw][oc]
__global__ __launch_bounds__(256) void repack_oihw_k(const float* __restrict__ w,
                                                     float* __restrict__ wt,
                                                     int OC, int IC, int KH, int KW)
{
    int i = blockIdx.x * 256 + threadIdx.x;
    int total = OC * IC * KH * KW;
    if (i >= total) return;
    int oc = i % OC; int t = i / OC;
    int kw = t % KW; int kh = (t / KW) % KH; int c = t / (KW * KH);
    wt[i] = w[((oc * IC + c) * KH + kh) * KW + kw];
}

// repack IOHW (transposed-conv weights) -> [c][kh][kw][oc]
__global__ __launch_bounds__(256) void repack_iohw_k(const float* __restrict__ w,
                                                     float* __restrict__ wt,
                                                     int IC, int OC, int KH, int KW)
{
    int i = blockIdx.x * 256 + threadIdx.x;
    int total = OC * IC * KH * KW;
    if (i >= total) return;
    int oc = i % OC; int t = i / OC;
    int kw = t % KW; int kh = (t / KW) % KH; int c = t / (KW * KH);
    wt[i] = w[((c * OC + oc) * KH + kh) * KW + kw];
}

__device__ __forceinline__ float fetch_oihw(const float* __restrict__ w, int j,
                                            int OC, int IC, int KH, int KW)
{
    int oc = j % OC; int t = j / OC;
    int kw = t % KW; int kh = (t / KW) % KH; int c = t / (KW * KH);
    return w[((oc * IC + c) * KH + kh) * KW + kw];
}

// all small-conv weights -> [c][kh][kw][oc], packed into one buffer
__global__ __launch_bounds__(256) void repack_small_k(
    const float* __restrict__ enc_w3, const float* __restrict__ er1,
    const float* __restrict__ er2, const float* __restrict__ pre_w,
    const float* __restrict__ dec_w1, const float* __restrict__ dr1,
    const float* __restrict__ dr2, float* __restrict__ dst)
{
    int i = blockIdx.x * 256 + threadIdx.x;
    if (i >= 557056) return;
    float v;
    if (i < 147456)       v = fetch_oihw(enc_w3,        i,          128, 128, 3, 3);
    else if (i < 221184)  v = fetch_oihw(er1,           i - 147456,  64, 128, 3, 3);
    else if (i < 294912)  v = fetch_oihw(er1 + 73728,   i - 221184,  64, 128, 3, 3);
    else if (i < 303104)  v = fetch_oihw(er2,           i - 294912, 128,  64, 1, 1);
    else if (i < 311296)  v = fetch_oihw(er2 + 8192,    i - 303104, 128,  64, 1, 1);
    else if (i < 319488)  v = fetch_oihw(pre_w,         i - 311296,  64, 128, 1, 1);
    else if (i < 393216)  v = fetch_oihw(dec_w1,        i - 319488, 128,  64, 3, 3);
    else if (i < 466944)  v = fetch_oihw(dr1,           i - 393216,  64, 128, 3, 3);
    else if (i < 540672)  v = fetch_oihw(dr1 + 73728,   i - 466944,  64, 128, 3, 3);
    else if (i < 548864)  v = fetch_oihw(dr2,           i - 540672, 128,  64, 1, 1);
    else                  v = fetch_oihw(dr2 + 8192,    i - 548864, 128,  64, 1, 1);
    dst[i] = v;
}

// conv2: h1(32,64,50,66) wt[c64][kh12][kw12][oc128] s10 p1 -> y(32,128,5,6), +b, relu
__global__ __launch_bounds__(512) void conv2_k2(const float* __restrict__ x,
                                                const float* __restrict__ wt,
                                                const float* __restrict__ b,
                                                float* __restrict__ y)
{
    __shared__ float xs[16 * 12 * 64];   // 49.2 KB
    __shared__ float sred[4 * 128 * 6];  // 12.3 KB
    const int tid = threadIdx.x;
    const int oc = tid & 127, sub = tid >> 7;  // sub = kh triplet
    const int n = blockIdx.x / 5, oh = blockIdx.x % 5;
    const int ih0 = oh * 10 - 1;
    float acc[6] = {0, 0, 0, 0, 0, 0};
    for (int cc = 0; cc < 4; ++cc) {
        __syncthreads();
        for (int i = tid; i < 12288; i += 512) {
            int col = i & 63; int t2 = i >> 6;
            int r = t2 % 12; int c = t2 / 12;
            int ih = ih0 + r, iw = col - 1;
            float v = 0.f;
            if (ih >= 0 && ih < 50 && iw >= 0 && iw < 66)
                v = x[((n * 64 + cc * 16 + c) * 50 + ih) * 66 + iw];
            xs[i] = v;
        }
        __syncthreads();
        for (int c = 0; c < 16; ++c) {
            for (int kh = sub * 3; kh < sub * 3 + 3; ++kh) {
                float xr[64];
                #pragma unroll
                for (int k = 0; k < 16; ++k)
                    *(float4*)&xr[4 * k] = *(const float4*)&xs[(c * 12 + kh) * 64 + 4 * k];
                const float* wp = wt + ((cc * 16 + c) * 144 + kh * 12) * 128 + oc;
                #pragma unroll
                for (int kw = 0; kw < 12; ++kw) {
                    float wv = wp[kw * 128];
                    #pragma unroll
                    for (int ow = 0; ow < 6; ++ow)
                        acc[ow] += xr[ow * 10 + kw] * wv;
                }
            }
        }
    }
    for (int j = 0; j < 6; ++j) sred[(sub * 128 + oc) * 6 + j] = acc[j];
    __syncthreads();
    if (sub == 0) {
        float bias = b[oc];
        #pragma unroll
        for (int j = 0; j < 6; ++j) {
            float v = acc[j] + sred[(128 + oc) * 6 + j] + sred[(256 + oc) * 6 + j]
                    + sred[(384 + oc) * 6 + j] + bias;
            y[((n * 128 + oc) * 5 + oh) * 6 + j] = fmaxf(v, 0.f);
        }
    }
}

// ---------------- fused 5x6 chain ----------------

template<int CIN, int COUT, bool RELU_IN>
__device__ __forceinline__ void conv3x3_lds(const float* __restrict__ src,
                                            const float* __restrict__ w,
                                            const float* __restrict__ bias,
                                            float* __restrict__ dst, int tid)
{
    constexpr int G = 512 / COUT;
    const int oc = tid % COUT;
    const int g  = tid / COUT;
    const int px0 = (30 * g) / G;
    const int np  = (30 * (g + 1)) / G - px0;
    float bv = bias ? bias[oc] : 0.f;
    float acc[8];
    #pragma unroll
    for (int j = 0; j < 8; ++j) acc[j] = bv;
    for (int c = 0; c < CIN; ++c) {
        const float* wc = w + c * 9 * COUT + oc;
        const float* sc = src + c * 30;
        #pragma unroll
        for (int kh = 0; kh < 3; ++kh) {
            #pragma unroll
            for (int kw = 0; kw < 3; ++kw) {
                float wv = wc[(kh * 3 + kw) * COUT];
                #pragma unroll
                for (int j = 0; j < 8; ++j) {
                    if (j < np) {
                        int px = px0 + j;
                        int oh = px / 6, ow = px - oh * 6;
                        int ih = oh + kh - 1, iw = ow + kw - 1;
                        if ((unsigned)ih < 5u && (unsigned)iw < 6u) {
                            float xv = sc[ih * 6 + iw];
                            if (RELU_IN) xv = fmaxf(xv, 0.f);
                            acc[j] += xv * wv;
                        }
                    }
                }
            }
        }
    }
    #pragma unroll
    for (int j = 0; j < 8; ++j)
        if (j < np) dst[oc * 30 + px0 + j] = acc[j];
}

template<int CIN, int COUT, bool RELU_IN, bool ACCUM>
__device__ __forceinline__ void conv1x1_lds(const float* __restrict__ src,
                                            const float* __restrict__ w,
                                            const float* __restrict__ bias,
                                            float* __restrict__ dst, int tid)
{
    constexpr int G = 512 / COUT;
    const int oc = tid % COUT;
    const int g  = tid / COUT;
    const int px0 = (30 * g) / G;
    const int np  = (30 * (g + 1)) / G - px0;
    float bv = bias ? bias[oc] : 0.f;
    float acc[8];
    #pragma unroll
    for (int j = 0; j < 8; ++j) acc[j] = bv;
    for (int c = 0; c < CIN; ++c) {
        float wv = w[c * COUT + oc];
        #pragma unroll
        for (int j = 0; j < 8; ++j) {
            if (j < np) {
                float xv = src[c * 30 + px0 + j];
                if (RELU_IN) xv = fmaxf(xv, 0.f);
                acc[j] += xv * wv;
            }
        }
    }
    #pragma unroll
    for (int j = 0; j < 8; ++j) {
        if (j < np) {
            if (ACCUM) dst[oc * 30 + px0 + j] += acc[j];
            else       dst[oc * 30 + px0 + j] = acc[j];
        }
    }
}

// chain: h2 -> enc3 -> resx2 -> pre -> VQ -> dec1 -> resx2 -> relu+pad -> xpad
__global__ __launch_bounds__(512) void chain_k(
    const float* __restrict__ h2, const float* __restrict__ wsm,
    const float* __restrict__ enc_b3, const float* __restrict__ pre_b,
    const float* __restrict__ emb, const float* __restrict__ dec_b1,
    float* __restrict__ xpad, float* __restrict__ counts,
    float* __restrict__ loss_sum)
{
    __shared__ float A[3840], B[3840], T[1920], Z[1920];
    const int n = blockIdx.x;
    const int tid = threadIdx.x;
    for (int i = tid; i < 3840; i += 512) A[i] = h2[n * 3840 + i];
    __syncthreads();
    conv3x3_lds<128, 128, false>(A, wsm, enc_b3, B, tid);          // enc3 (+b, no relu)
    __syncthreads();
    conv3x3_lds<128, 64, true>(B, wsm + 147456, nullptr, T, tid);  // enc res0 conv3x3
    __syncthreads();
    conv1x1_lds<64, 128, true, true>(T, wsm + 294912, nullptr, B, tid);
    __syncthreads();
    conv3x3_lds<128, 64, true>(B, wsm + 221184, nullptr, T, tid);  // enc res1
    __syncthreads();
    conv1x1_lds<64, 128, true, true>(T, wsm + 303104, nullptr, B, tid);
    __syncthreads();
    conv1x1_lds<128, 64, true, false>(B, wsm + 311296, pre_b, Z, tid); // pre -> z
    __syncthreads();
    // --- VQ: wave per pixel ---
    const int lane = tid & 63, wid = tid >> 6;
    for (int px = wid; px < 30; px += 8) {
        float zr[64];
        #pragma unroll
        for (int d = 0; d < 64; ++d) zr[d] = Z[d * 30 + px];
        float best = 1e30f; int bestk = 0;
        for (int jk = 0; jk < 8; ++jk) {
            int k = lane + jk * 64;
            const float* ep = emb + k * 64;
            float dist = 0.f;
            #pragma unroll 8
            for (int d = 0; d < 64; ++d) { float df = ep[d] - zr[d]; dist += df * df; }
            if (dist < best) { best = dist; bestk = k; }
        }
        for (int off = 32; off; off >>= 1) {
            float ob = __shfl_down(best, off); int ok = __shfl_down(bestk, off);
            if (ob < best || (ob == best && ok < bestk)) { best = ob; bestk = ok; }
        }
        bestk = __shfl(bestk, 0);
        float ev = emb[bestk * 64 + lane];
        T[lane * 30 + px] = ev;                       // q
        float df = ev - Z[lane * 30 + px]; df *= df;
        for (int off = 32; off; off >>= 1) df += __shfl_down(df, off);
        if (lane == 0) { atomicAdd(loss_sum, df); atomicAdd(&counts[bestk], 1.f); }
    }
    __syncthreads();
    conv3x3_lds<64, 128, false>(T, wsm + 319488, dec_b1, A, tid);  // dec1 (q, no relu)
    __syncthreads();
    conv3x3_lds<128, 64, true>(A, wsm + 393216, nullptr, T, tid);  // dec res0
    __syncthreads();
    conv1x1_lds<64, 128, true, true>(T, wsm + 540672, nullptr, A, tid);
    __syncthreads();
    conv3x3_lds<128, 64, true>(A, wsm + 466944, nullptr, T, tid);  // dec res1
    __syncthreads();
    conv1x1_lds<64, 128, true, true>(T, wsm + 548864, nullptr, A, tid);
    __syncthreads();
    // final relu + zero-pad to xpad[n][128][7][8]
    for (int i = tid; i < 7168; i += 512) {
        int col = i & 7, r = (i >> 3) % 7, c = i / 56;
        float v = 0.f;
        if (r >= 1 && r <= 5 && col >= 1 && col <= 6)
            v = fmaxf(A[c * 30 + (r - 1) * 6 + col - 1], 0.f);
        xpad[n * 7168 + i] = v;
    }
}

// ---------------- convt1 ----------------

template<bool TR, bool TS>
__device__ __forceinline__ void ct1_accum(const float* __restrict__ xs0,
                                          const float* __restrict__ xs1,
                                          const float* __restrict__ wt,
                                          int R, int S, int m0, int lane,
                                          float acc[6])
{
    #pragma unroll 2
    for (int c = 0; c < 128; ++c) {
        float x1[7], x0[7];
        #pragma unroll
        for (int k = 0; k < 7; ++k) x1[k] = xs1[c * 8 + m0 + k];
        if (TR) {
            #pragma unroll
            for (int k = 0; k < 7; ++k) x0[k] = xs0[c * 8 + m0 + k];
        }
        float wA = wt[(c * 144 + R * 12 + S) * 64 + lane];
        #pragma unroll
        for (int j = 0; j < 6; ++j) acc[j] += x1[j + 1] * wA;
        if (TS) {
            float wB = wt[(c * 144 + R * 12 + S + 10) * 64 + lane];
            #pragma unroll
            for (int j = 0; j < 6; ++j) acc[j] += x1[j] * wB;
        }
        if (TR) {
            float wC = wt[(c * 144 + (R + 10) * 12 + S) * 64 + lane];
            #pragma unroll
            for (int j = 0; j < 6; ++j) acc[j] += x0[j + 1] * wC;
            if (TS) {
                float wD = wt[(c * 144 + (R + 10) * 12 + S + 10) * 64 + lane];
                #pragma unroll
                for (int j = 0; j < 6; ++j) acc[j] += x0[j] * wD;
            }
        }
    }
}

// convt1: xpad(32,128,7,8) wt[c128][12][12][oc64] s10 p1 -> dmid_pad[32][64][52][62]
__global__ __launch_bounds__(256) void convt1_k3(const float* __restrict__ xp,
                                                 const float* __restrict__ wt,
                                                 const float* __restrict__ b,
                                                 float* __restrict__ y)
{
    __shared__ float xs[2][128][8];   // 8 KB
    const int bi = blockIdx.x;        // 32*50
    const int n = bi / 50, oh = bi % 50;
    const int q = (oh + 1) / 10, R = (oh + 1) % 10;
    const int tid = threadIdx.x;
    for (int i = tid; i < 2048; i += 256) {
        int col = i & 7, c = (i >> 3) & 127, r = i >> 10;
        ((float*)xs)[i] = xp[((n * 128 + c) * 7 + q + r) * 8 + col];
    }
    __syncthreads();
    const int lane = tid & 63, wv = tid >> 6;
    const float bias = b[lane];
    const float* xs0 = &xs[0][0][0];
    const float* xs1 = &xs[1][0][0];
    for (int si = 0; si < 3; ++si) {
        int S = wv + si * 4;
        if (S >= 10) break;
        int m0 = (S == 0) ? 1 : 0;
        float acc[6] = {0, 0, 0, 0, 0, 0};
        if (R < 2) {
            if (S < 2) ct1_accum<true, true>(xs0, xs1, wt, R, S, m0, lane, acc);
            else       ct1_accum<true, false>(xs0, xs1, wt, R, S, m0, lane, acc);
        } else {
            if (S < 2) ct1_accum<false, true>(xs0, xs1, wt, R, S, m0, lane, acc);
            else       ct1_accum<false, false>(xs0, xs1, wt, R, S, m0, lane, acc);
        }
        float* yp = y + ((n * 64 + lane) * 52 + oh + 1) * 62 + 10 * m0 + S;
        #pragma unroll
        for (int j = 0; j < 6; ++j) yp[10 * j] = fmaxf(acc[j] + bias, 0.f);
    }
}

// ---------------- convt2 ----------------

template<bool TR, bool TS>
__device__ __forceinline__ void ct2_accum(const float* __restrict__ xs0,
                                          const float* __restrict__ xs1,
                                          const float* __restrict__ wt2,
                                          int R, int S, int m,
                                          float& a0, float& a1)
{
    #pragma unroll 4
    for (int c = 0; c < 64; ++c) {
        float x1a = xs1[c * 64 + m + 1];
        float2 wA = *(const float2*)&wt2[(c * 110 + R * 11 + S) * 2];
        a0 += x1a * wA.x; a1 += x1a * wA.y;
        if (TS) {
            float x1b = xs1[c * 64 + m];
            float2 wB = *(const float2*)&wt2[(c * 110 + R * 11 + S + 9) * 2];
            a0 += x1b * wB.x; a1 += x1b * wB.y;
        }
        if (TR) {
            float x0a = xs0[c * 64 + m + 1];
            float2 wC = *(const float2*)&wt2[(c * 110 + (R + 8) * 11 + S) * 2];
            a0 += x0a * wC.x; a1 += x0a * wC.y;
            if (TS) {
                float x0b = xs0[c * 64 + m];
                float2 wD = *(const float2*)&wt2[(c * 110 + (R + 8) * 11 + S + 9) * 2];
                a0 += x0b * wD.x; a1 += x0b * wD.y;
            }
        }
    }
}

// convt2: dmid_pad[32][64][52][62] wt2[c64][10][11][oc2] s(8,9) p1 -> out(32,2,400,540)+b
__global__ __launch_bounds__(256) void convt2_k3(const float* __restrict__ xd,
                                                 const float* __restrict__ wt2,
                                                 const float* __restrict__ bb,
                                                 float* __restrict__ out)
{
    __shared__ float xs[2][64][64];   // 32 KB
    const int bi = blockIdx.x;        // 32*51
    const int n = bi / 51, io = bi % 51;
    const int tid = threadIdx.x;
    for (int i = tid; i < 2 * 64 * 64; i += 256) {
        int col = i & 63, c = (i >> 6) & 63, r = i >> 12;
        float v = 0.f;
        if (col < 62) v = xd[((n * 64 + c) * 52 + io + r) * 62 + col];
        ((float*)xs)[i] = v;
    }
    __syncthreads();
    const float b0 = bb[0], b1 = bb[1];
    const int lane = tid & 63, wv = tid >> 6;
    if (lane >= 60) return;
    const float* xs0 = &xs[0][0][0];
    const float* xs1 = &xs[1][0][0];
    for (int pp = 0; pp < 18; ++pp) {
        int p = wv * 18 + pp;
        int R = p / 9, S = p % 9;
        int oh = 8 * io + R - 1;
        if (oh < 0 || oh >= 400) continue;
        int m = lane + ((S == 0) ? 1 : 0);
        float a0 = 0.f, a1 = 0.f;
        if (R < 2) {
            if (S < 2) ct2_accum<true, true>(xs0, xs1, wt2, R, S, m, a0, a1);
            else       ct2_accum<true, false>(xs0, xs1, wt2, R, S, m, a0, a1);
        } else {
            if (S < 2) ct2_accum<false, true>(xs0, xs1, wt2, R, S, m, a0, a1);
            else       ct2_accum<false, false>(xs0, xs1, wt2, R, S, m, a0, a1);
        }
        int ow = 9 * m + S - 1;
        float* yp = out + ((size_t)(n * 2) * 400 + oh) * 540 + ow;
        yp[0] = a0 + b0;
        yp[400 * 540] = a1 + b1;
    }
}

// finalize
__global__ __launch_bounds__(512) void fin_k(const float* __restrict__ counts,
                                             const float* __restrict__ loss_sum,
                                             float* __restrict__ out, int out_size)
{
    __shared__ float red[512];
    int t = threadIdx.x;
    float c = counts[t];
    float p = c * (1.0f / 960.0f);
    red[t] = p * logf(p + 1e-10f);
    __syncthreads();
    for (int s = 256; s > 0; s >>= 1) {
        if (t < s) red[t] += red[t + s];
        __syncthreads();
    }
    if (t == 0) {
        out[out_size - 1] = expf(-red[0]);
        out[0] = loss_sum[0] * 1.25f / 61440.0f;
    }
}

extern "C" void kernel_launch(void* const* d_in, const int* in_sizes, int n_in,
                              void* d_out, int out_size, void* d_ws, size_t ws_size,
                              hipStream_t stream)
{
    const float* x          = (const float*)d_in[0];
    const float* enc_w1     = (const float*)d_in[1];
    const float* enc_b1     = (const float*)d_in[2];
    const float* enc_w2     = (const float*)d_in[3];
    const float* enc_b2     = (const float*)d_in[4];
    const float* enc_w3     = (const float*)d_in[5];
    const float* enc_b3     = (const float*)d_in[6];
    const float* enc_res_w1 = (const float*)d_in[7];
    const float* enc_res_w2 = (const float*)d_in[8];
    const float* pre_w      = (const float*)d_in[9];
    const float* pre_b      = (const float*)d_in[10];
    const float* emb        = (const float*)d_in[11];
    const float* dec_w1     = (const float*)d_in[12];
    const float* dec_b1     = (const float*)d_in[13];
    const float* dec_res_w1 = (const float*)d_in[14];
    const float* dec_res_w2 = (const float*)d_in[15];
    const float* dec_tw1    = (const float*)d_in[16];
    const float* dec_tb1    = (const float*)d_in[17];
    const float* dec_tw2    = (const float*)d_in[18];
    const float* dec_tb2    = (const float*)d_in[19];

    float* ws  = (float*)d_ws;
    float* out = (float*)d_out;

    float* h1       = ws;            // (32,64,50,66) = 6,758,400; later dmid_pad
    float* dmid     = ws;            // padded (32,64,52,62) = 6,602,752
    float* h2       = ws + 6758400;  // (32,128,5,6) = 122,880
    float* counts   = ws + 6881280;  // 512
    float* loss_sum = ws + 6881792;  // 1 (+pad to 64)
    float* wtA      = ws + 6881856;  // 1,179,648 (conv2 repack, then convt1 repack)
    float* wt2      = ws + 8061504;  // 14,080
    float* xpad     = ws + 8075584;  // 229,376
    float* wsm      = ws + 8304960;  // 557,056 -> end 8,862,016 floats (35.4 MB)

    hipMemsetAsync(counts, 0, 513 * sizeof(float), stream);

    // --- encoder ---
    repack_oihw_k<<<4608, 256, 0, stream>>>(enc_w2, wtA, 128, 64, 12, 12);
    conv1_k<<<1600, 256, 0, stream>>>(x, enc_w1, enc_b1, h1);
    conv2_k2<<<160, 512, 0, stream>>>(h1, wtA, enc_b2, h2);

    // --- fused 5x6 chain (enc3..VQ..dec res) ---
    repack_small_k<<<2176, 256, 0, stream>>>(enc_w3, enc_res_w1, enc_res_w2, pre_w,
                                             dec_w1, dec_res_w1, dec_res_w2, wsm);
    chain_k<<<32, 512, 0, stream>>>(h2, wsm, enc_b3, pre_b, emb, dec_b1,
                                    xpad, counts, loss_sum);

    // --- decoder transposed convs ---
    repack_iohw_k<<<4608, 256, 0, stream>>>(dec_tw1, wtA, 128, 64, 12, 12);
    repack_iohw_k<<<55, 256, 0, stream>>>(dec_tw2, wt2, 64, 2, 10, 11);
    hipMemsetAsync(dmid, 0, (size_t)6602752 * sizeof(float), stream);
    convt1_k3<<<1600, 256, 0, stream>>>(xpad, wtA, dec_tb1, dmid);
    convt2_k3<<<1632, 256, 0, stream>>>(dmid, wt2, dec_tb2, out + 1);

    fin_k<<<1, 512, 0, stream>>>(counts, loss_sum, out, out_size);
}

// Round 7
// 2249.459 us; speedup vs baseline: 1.7557x; 1.7557x over previous
//
#include <hip/hip_runtime.h>
#include <math.h>

// ---------------------------------------------------------------------------
// VQ-VAE forward. Round 6 (resubmit after container failure): chain_k with
// LDS-staged weight slabs, 1024 threads; convt1/convt2 LDS-x phase kernels.
// ---------------------------------------------------------------------------

// conv1: x(32,2,400,600) w(64,2,10,11) s(8,9) p(1,1) -> y(32,64,50,66), +b, relu
__global__ __launch_bounds__(256) void conv1_k(const float* __restrict__ x,
                                               const float* __restrict__ w,
                                               const float* __restrict__ b,
                                               float* __restrict__ y)
{
    __shared__ float xs[2 * 10 * 596]; // 47.68 KB
    const int blk = blockIdx.x;            // 32*50 = 1600
    const int n = blk / 50, oh = blk % 50;
    const int tid = threadIdx.x;
    const int ih0 = oh * 8 - 1;
    for (int i = tid; i < 2 * 10 * 596; i += 256) {
        int c = i / 5960, rem = i % 5960;
        int r = rem / 596, j = rem % 596;
        int ih = ih0 + r, iw = j - 1;
        float v = 0.f;
        if (ih >= 0 && ih < 400 && iw >= 0 && iw < 600)
            v = x[((n * 2 + c) * 400 + ih) * 600 + iw];
        xs[i] = v;
    }
    __syncthreads();
    for (int i = tid; i < 32 * 66; i += 256) {
        int oc = i / 66, ow = i % 66;
        int col = ow * 9;
        float a0 = 0.f, a1 = 0.f;
        for (int c = 0; c < 2; ++c) {
            const float* wp0 = w + ((oc)      * 2 + c) * 110;
            const float* wp1 = w + ((oc + 32) * 2 + c) * 110;
            const float* xp  = xs + c * 5960 + col;
            for (int kh = 0; kh < 10; ++kh) {
                #pragma unroll
                for (int kw = 0; kw < 11; ++kw) {
                    float xv = xp[kh * 596 + kw];
                    a0 += xv * wp0[kh * 11 + kw];
                    a1 += xv * wp1[kh * 11 + kw];
                }
            }
        }
        y[((n * 64 + oc)      * 50 + oh) * 66 + ow] = fmaxf(a0 + b[oc], 0.f);
        y[((n * 64 + oc + 32) * 50 + oh) * 66 + ow] = fmaxf(a1 + b[oc + 32], 0.f);
    }
}

// repack OIHW -> [c][kh][kw][oc]
__global__ __launch_bounds__(256) void repack_oihw_k(const float* __restrict__ w,
                                                     float* __restrict__ wt,
                                                     int OC, int IC, int KH, int KW)
{
    int i = blockIdx.x * 256 + threadIdx.x;
    int total = OC * IC * KH * KW;
    if (i >= total) return;
    int oc = i % OC; int t = i / OC;
    int kw = t % KW; int kh = (t / KW) % KH; int c = t / (KW * KH);
    wt[i] = w[((oc * IC + c) * KH + kh) * KW + kw];
}

// repack IOHW (transposed-conv weights) -> [c][kh][kw][oc]
__global__ __launch_bounds__(256) void repack_iohw_k(const float* __restrict__ w,
                                                     float* __restrict__ wt,
                                                     int IC, int OC, int KH, int KW)
{
    int i = blockIdx.x * 256 + threadIdx.x;
    int total = OC * IC * KH * KW;
    if (i >= total) return;
    int oc = i % OC; int t = i / OC;
    int kw = t % KW; int kh = (t / KW) % KH; int c = t / (KW * KH);
    wt[i] = w[((c * OC + oc) * KH + kh) * KW + kw];
}

__device__ __forceinline__ float fetch_oihw(const float* __restrict__ w, int j,
                                            int OC, int IC, int KH, int KW)
{
    int oc = j % OC; int t = j / OC;
    int kw = t % KW; int kh = (t / KW) % KH; int c = t / (KW * KH);
    return w[((oc * IC + c) * KH + kh) * KW + kw];
}

// all small-conv weights -> [c][kh][kw][oc], packed into one buffer
__global__ __launch_bounds__(256) void repack_small_k(
    const float* __restrict__ enc_w3, const float* __restrict__ er1,
    const float* __restrict__ er2, const float* __restrict__ pre_w,
    const float* __restrict__ dec_w1, const float* __restrict__ dr1,
    const float* __restrict__ dr2, float* __restrict__ dst)
{
    int i = blockIdx.x * 256 + threadIdx.x;
    if (i >= 557056) return;
    float v;
    if (i < 147456)       v = fetch_oihw(enc_w3,        i,          128, 128, 3, 3);
    else if (i < 221184)  v = fetch_oihw(er1,           i - 147456,  64, 128, 3, 3);
    else if (i < 294912)  v = fetch_oihw(er1 + 73728,   i - 221184,  64, 128, 3, 3);
    else if (i < 303104)  v = fetch_oihw(er2,           i - 294912, 128,  64, 1, 1);
    else if (i < 311296)  v = fetch_oihw(er2 + 8192,    i - 303104, 128,  64, 1, 1);
    else if (i < 319488)  v = fetch_oihw(pre_w,         i - 311296,  64, 128, 1, 1);
    else if (i < 393216)  v = fetch_oihw(dec_w1,        i - 319488, 128,  64, 3, 3);
    else if (i < 466944)  v = fetch_oihw(dr1,           i - 393216,  64, 128, 3, 3);
    else if (i < 540672)  v = fetch_oihw(dr1 + 73728,   i - 466944,  64, 128, 3, 3);
    else if (i < 548864)  v = fetch_oihw(dr2,           i - 540672, 128,  64, 1, 1);
    else                  v = fetch_oihw(dr2 + 8192,    i - 548864, 128,  64, 1, 1);
    dst[i] = v;
}

// conv2: h1(32,64,50,66) wt[c64][kh12][kw12][oc128] s10 p1 -> y(32,128,5,6), +b, relu
__global__ __launch_bounds__(512) void conv2_k2(const float* __restrict__ x,
                                                const float* __restrict__ wt,
                                                const float* __restrict__ b,
                                                float* __restrict__ y)
{
    __shared__ float xs[16 * 12 * 64];   // 49.2 KB
    __shared__ float sred[4 * 128 * 6];  // 12.3 KB
    const int tid = threadIdx.x;
    const int oc = tid & 127, sub = tid >> 7;  // sub = kh triplet
    const int n = blockIdx.x / 5, oh = blockIdx.x % 5;
    const int ih0 = oh * 10 - 1;
    float acc[6] = {0, 0, 0, 0, 0, 0};
    for (int cc = 0; cc < 4; ++cc) {
        __syncthreads();
        for (int i = tid; i < 12288; i += 512) {
            int col = i & 63; int t2 = i >> 6;
            int r = t2 % 12; int c = t2 / 12;
            int ih = ih0 + r, iw = col - 1;
            float v = 0.f;
            if (ih >= 0 && ih < 50 && iw >= 0 && iw < 66)
                v = x[((n * 64 + cc * 16 + c) * 50 + ih) * 66 + iw];
            xs[i] = v;
        }
        __syncthreads();
        for (int c = 0; c < 16; ++c) {
            for (int kh = sub * 3; kh < sub * 3 + 3; ++kh) {
                float xr[64];
                #pragma unroll
                for (int k = 0; k < 16; ++k)
                    *(float4*)&xr[4 * k] = *(const float4*)&xs[(c * 12 + kh) * 64 + 4 * k];
                const float* wp = wt + ((cc * 16 + c) * 144 + kh * 12) * 128 + oc;
                #pragma unroll
                for (int kw = 0; kw < 12; ++kw) {
                    float wv = wp[kw * 128];
                    #pragma unroll
                    for (int ow = 0; ow < 6; ++ow)
                        acc[ow] += xr[ow * 10 + kw] * wv;
                }
            }
        }
    }
    for (int j = 0; j < 6; ++j) sred[(sub * 128 + oc) * 6 + j] = acc[j];
    __syncthreads();
    if (sub == 0) {
        float bias = b[oc];
        #pragma unroll
        for (int j = 0; j < 6; ++j) {
            float v = acc[j] + sred[(128 + oc) * 6 + j] + sred[(256 + oc) * 6 + j]
                    + sred[(384 + oc) * 6 + j] + bias;
            y[((n * 128 + oc) * 5 + oh) * 6 + j] = fmaxf(v, 0.f);
        }
    }
}

// ---------------- fused 5x6 chain (v2: LDS weight chunks, 1024 thr) ----------------

template<int CIN, int COUT, bool RELU_IN>
__device__ __forceinline__ void conv3x3_stage(const float* __restrict__ src,
                                              const float* __restrict__ wg,
                                              const float* __restrict__ bias,
                                              float* __restrict__ dst,
                                              float* __restrict__ WS, int tid)
{
    constexpr int G  = 1024 / COUT;          // 8 or 16
    constexpr int NP = (30 + G - 1) / G;     // 4 or 2
    const int oc = tid % COUT;
    const int g  = tid / COUT;
    const int px0 = (30 * g) / G;
    const int np  = (30 * (g + 1)) / G - px0;
    float acc[NP];
    float bv = bias ? bias[oc] : 0.f;
    #pragma unroll
    for (int j = 0; j < NP; ++j) acc[j] = bv;
    for (int cc0 = 0; cc0 < CIN; cc0 += 16) {
        __syncthreads();
        const float* wsrc = wg + cc0 * 9 * COUT;
        for (int i = tid; i < 16 * 9 * COUT; i += 1024) WS[i] = wsrc[i];
        __syncthreads();
        for (int c = 0; c < 16; ++c) {
            const float* sc = src + (cc0 + c) * 30;
            const float* wc = WS + c * 9 * COUT + oc;
            #pragma unroll
            for (int kh = 0; kh < 3; ++kh) {
                #pragma unroll
                for (int kw = 0; kw < 3; ++kw) {
                    float wv = wc[(kh * 3 + kw) * COUT];
                    #pragma unroll
                    for (int j = 0; j < NP; ++j) {
                        if (j < np) {
                            int px = px0 + j;
                            int oh = px / 6, ow = px - oh * 6;
                            int ih = oh + kh - 1, iw = ow + kw - 1;
                            if ((unsigned)ih < 5u && (unsigned)iw < 6u) {
                                float xv = sc[ih * 6 + iw];
                                if (RELU_IN) xv = fmaxf(xv, 0.f);
                                acc[j] += xv * wv;
                            }
                        }
                    }
                }
            }
        }
    }
    #pragma unroll
    for (int j = 0; j < NP; ++j)
        if (j < np) dst[oc * 30 + px0 + j] = acc[j];
}

template<int CIN, int COUT, bool RELU_IN, bool ACCUM>
__device__ __forceinline__ void conv1x1_stage(const float* __restrict__ src,
                                              const float* __restrict__ wg,
                                              const float* __restrict__ bias,
                                              float* __restrict__ dst,
                                              float* __restrict__ WS, int tid)
{
    constexpr int G  = 1024 / COUT;
    constexpr int NP = (30 + G - 1) / G;
    const int oc = tid % COUT;
    const int g  = tid / COUT;
    const int px0 = (30 * g) / G;
    const int np  = (30 * (g + 1)) / G - px0;
    __syncthreads();
    for (int i = tid; i < CIN * COUT; i += 1024) WS[i] = wg[i];
    __syncthreads();
    float acc[NP];
    float bv = bias ? bias[oc] : 0.f;
    #pragma unroll
    for (int j = 0; j < NP; ++j) acc[j] = bv;
    for (int c = 0; c < CIN; ++c) {
        float wv = WS[c * COUT + oc];
        #pragma unroll
        for (int j = 0; j < NP; ++j) {
            if (j < np) {
                float xv = src[c * 30 + px0 + j];
                if (RELU_IN) xv = fmaxf(xv, 0.f);
                acc[j] += xv * wv;
            }
        }
    }
    #pragma unroll
    for (int j = 0; j < NP; ++j) {
        if (j < np) {
            if (ACCUM) dst[oc * 30 + px0 + j] += acc[j];
            else       dst[oc * 30 + px0 + j] = acc[j];
        }
    }
}

// chain: h2 -> enc3 -> resx2 -> pre -> VQ -> dec1 -> resx2 -> relu+pad -> xpad
__global__ __launch_bounds__(1024) void chain_k(
    const float* __restrict__ h2, const float* __restrict__ wsm,
    const float* __restrict__ enc_b3, const float* __restrict__ pre_b,
    const float* __restrict__ emb, const float* __restrict__ dec_b1,
    float* __restrict__ xpad, float* __restrict__ counts,
    float* __restrict__ loss_sum)
{
    __shared__ float A[3840], B[3840], T[1920], Z[1920];
    __shared__ float WS[16 * 9 * 128];   // 73.7 KB weight slab
    const int n = blockIdx.x;
    const int tid = threadIdx.x;
    for (int i = tid; i < 3840; i += 1024) A[i] = h2[n * 3840 + i];
    // enc3 (+b, no relu on input)
    conv3x3_stage<128, 128, false>(A, wsm, enc_b3, B, WS, tid);
    // enc res0
    conv3x3_stage<128, 64, true>(B, wsm + 147456, nullptr, T, WS, tid);
    conv1x1_stage<64, 128, true, true>(T, wsm + 294912, nullptr, B, WS, tid);
    // enc res1
    conv3x3_stage<128, 64, true>(B, wsm + 221184, nullptr, T, WS, tid);
    conv1x1_stage<64, 128, true, true>(T, wsm + 303104, nullptr, B, WS, tid);
    // pre -> z
    conv1x1_stage<128, 64, true, false>(B, wsm + 311296, pre_b, Z, WS, tid);
    __syncthreads();
    // --- VQ: wave per pixel ---
    const int lane = tid & 63, wid = tid >> 6;
    for (int px = wid; px < 30; px += 16) {
        float zr[64];
        #pragma unroll
        for (int d = 0; d < 64; ++d) zr[d] = Z[d * 30 + px];
        float best = 1e30f; int bestk = 0;
        for (int jk = 0; jk < 8; ++jk) {
            int k = lane + jk * 64;
            const float* ep = emb + k * 64;
            float dist = 0.f;
            #pragma unroll 8
            for (int d = 0; d < 64; ++d) { float df = ep[d] - zr[d]; dist += df * df; }
            if (dist < best) { best = dist; bestk = k; }
        }
        for (int off = 32; off; off >>= 1) {
            float ob = __shfl_down(best, off); int ok = __shfl_down(bestk, off);
            if (ob < best || (ob == best && ok < bestk)) { best = ob; bestk = ok; }
        }
        bestk = __shfl(bestk, 0);
        float ev = emb[bestk * 64 + lane];
        T[lane * 30 + px] = ev;                       // q
        float df = ev - Z[lane * 30 + px]; df *= df;
        for (int off = 32; off; off >>= 1) df += __shfl_down(df, off);
        if (lane == 0) { atomicAdd(loss_sum, df); atomicAdd(&counts[bestk], 1.f); }
    }
    __syncthreads();
    // dec1 (input q, no relu)
    conv3x3_stage<64, 128, false>(T, wsm + 319488, dec_b1, A, WS, tid);
    // dec res0
    conv3x3_stage<128, 64, true>(A, wsm + 393216, nullptr, T, WS, tid);
    conv1x1_stage<64, 128, true, true>(T, wsm + 540672, nullptr, A, WS, tid);
    // dec res1
    conv3x3_stage<128, 64, true>(A, wsm + 466944, nullptr, T, WS, tid);
    conv1x1_stage<64, 128, true, true>(T, wsm + 548864, nullptr, A, WS, tid);
    __syncthreads();
    // final relu + zero-pad to xpad[n][128][7][8]
    for (int i = tid; i < 7168; i += 1024) {
        int col = i & 7, r = (i >> 3) % 7, c = i / 56;
        float v = 0.f;
        if (r >= 1 && r <= 5 && col >= 1 && col <= 6)
            v = fmaxf(A[c * 30 + (r - 1) * 6 + col - 1], 0.f);
        xpad[n * 7168 + i] = v;
    }
}

// ---------------- convt1 ----------------

template<bool TR, bool TS>
__device__ __forceinline__ void ct1_accum(const float* __restrict__ xs0,
                                          const float* __restrict__ xs1,
                                          const float* __restrict__ wt,
                                          int R, int S, int m0, int lane,
                                          float acc[6])
{
    #pragma unroll 2
    for (int c = 0; c < 128; ++c) {
        float x1[7], x0[7];
        #pragma unroll
        for (int k = 0; k < 7; ++k) x1[k] = xs1[c * 8 + m0 + k];
        if (TR) {
            #pragma unroll
            for (int k = 0; k < 7; ++k) x0[k] = xs0[c * 8 + m0 + k];
        }
        float wA = wt[(c * 144 + R * 12 + S) * 64 + lane];
        #pragma unroll
        for (int j = 0; j < 6; ++j) acc[j] += x1[j + 1] * wA;
        if (TS) {
            float wB = wt[(c * 144 + R * 12 + S + 10) * 64 + lane];
            #pragma unroll
            for (int j = 0; j < 6; ++j) acc[j] += x1[j] * wB;
        }
        if (TR) {
            float wC = wt[(c * 144 + (R + 10) * 12 + S) * 64 + lane];
            #pragma unroll
            for (int j = 0; j < 6; ++j) acc[j] += x0[j + 1] * wC;
            if (TS) {
                float wD = wt[(c * 144 + (R + 10) * 12 + S + 10) * 64 + lane];
                #pragma unroll
                for (int j = 0; j < 6; ++j) acc[j] += x0[j] * wD;
            }
        }
    }
}

// convt1: xpad(32,128,7,8) wt[c128][12][12][oc64] s10 p1 -> dmid_pad[32][64][52][62]
__global__ __launch_bounds__(256) void convt1_k3(const float* __restrict__ xp,
                                                 const float* __restrict__ wt,
                                                 const float* __restrict__ b,
                                                 float* __restrict__ y)
{
    __shared__ float xs[2][128][8];   // 8 KB
    const int bi = blockIdx.x;        // 32*50
    const int n = bi / 50, oh = bi % 50;
    const int q = (oh + 1) / 10, R = (oh + 1) % 10;
    const int tid = threadIdx.x;
    for (int i = tid; i < 2048; i += 256) {
        int col = i & 7, c = (i >> 3) & 127, r = i >> 10;
        ((float*)xs)[i] = xp[((n * 128 + c) * 7 + q + r) * 8 + col];
    }
    __syncthreads();
    const int lane = tid & 63, wv = tid >> 6;
    const float bias = b[lane];
    const float* xs0 = &xs[0][0][0];
    const float* xs1 = &xs[1][0][0];
    for (int si = 0; si < 3; ++si) {
        int S = wv + si * 4;
        if (S >= 10) break;
        int m0 = (S == 0) ? 1 : 0;
        float acc[6] = {0, 0, 0, 0, 0, 0};
        if (R < 2) {
            if (S < 2) ct1_accum<true, true>(xs0, xs1, wt, R, S, m0, lane, acc);
            else       ct1_accum<true, false>(xs0, xs1, wt, R, S, m0, lane, acc);
        } else {
            if (S < 2) ct1_accum<false, true>(xs0, xs1, wt, R, S, m0, lane, acc);
            else       ct1_accum<false, false>(xs0, xs1, wt, R, S, m0, lane, acc);
        }
        float* yp = y + ((n * 64 + lane) * 52 + oh + 1) * 62 + 10 * m0 + S;
        #pragma unroll
        for (int j = 0; j < 6; ++j) yp[10 * j] = fmaxf(acc[j] + bias, 0.f);
    }
}

// ---------------- convt2 ----------------

template<bool TR, bool TS>
__device__ __forceinline__ void ct2_accum(const float* __restrict__ xs0,
                                          const float* __restrict__ xs1,
                                          const float* __restrict__ wt2,
                                          int R, int S, int m,
                                          float& a0, float& a1)
{
    #pragma unroll 4
    for (int c = 0; c < 64; ++c) {
        float x1a = xs1[c * 64 + m + 1];
        float2 wA = *(const float2*)&wt2[(c * 110 + R * 11 + S) * 2];
        a0 += x1a * wA.x; a1 += x1a * wA.y;
        if (TS) {
            float x1b = xs1[c * 64 + m];
            float2 wB = *(const float2*)&wt2[(c * 110 + R * 11 + S + 9) * 2];
            a0 += x1b * wB.x; a1 += x1b * wB.y;
        }
        if (TR) {
            float x0a = xs0[c * 64 + m + 1];
            float2 wC = *(const float2*)&wt2[(c * 110 + (R + 8) * 11 + S) * 2];
            a0 += x0a * wC.x; a1 += x0a * wC.y;
            if (TS) {
                float x0b = xs0[c * 64 + m];
                float2 wD = *(const float2*)&wt2[(c * 110 + (R + 8) * 11 + S + 9) * 2];
                a0 += x0b * wD.x; a1 += x0b * wD.y;
            }
        }
    }
}

// convt2: dmid_pad[32][64][52][62] wt2[c64][10][11][oc2] s(8,9) p1 -> out(32,2,400,540)+b
__global__ __launch_bounds__(256) void convt2_k3(const float* __restrict__ xd,
                                                 const float* __restrict__ wt2,
                                                 const float* __restrict__ bb,
                                                 float* __restrict__ out)
{
    __shared__ float xs[2][64][64];   // 32 KB
    const int bi = blockIdx.x;        // 32*51
    const int n = bi / 51, io = bi % 51;
    const int tid = threadIdx.x;
    for (int i = tid; i < 2 * 64 * 64; i += 256) {
        int col = i & 63, c = (i >> 6) & 63, r = i >> 12;
        float v = 0.f;
        if (col < 62) v = xd[((n * 64 + c) * 52 + io + r) * 62 + col];
        ((float*)xs)[i] = v;
    }
    __syncthreads();
    const float b0 = bb[0], b1 = bb[1];
    const int lane = tid & 63, wv = tid >> 6;
    if (lane < 60) {
        const float* xs0 = &xs[0][0][0];
        const float* xs1 = &xs[1][0][0];
        for (int pp = 0; pp < 18; ++pp) {
            int p = wv * 18 + pp;
            int R = p / 9, S = p % 9;
            int oh = 8 * io + R - 1;
            if (oh < 0 || oh >= 400) continue;
            int m = lane + ((S == 0) ? 1 : 0);
            float a0 = 0.f, a1 = 0.f;
            if (R < 2) {
                if (S < 2) ct2_accum<true, true>(xs0, xs1, wt2, R, S, m, a0, a1);
                else       ct2_accum<true, false>(xs0, xs1, wt2, R, S, m, a0, a1);
            } else {
                if (S < 2) ct2_accum<false, true>(xs0, xs1, wt2, R, S, m, a0, a1);
                else       ct2_accum<false, false>(xs0, xs1, wt2, R, S, m, a0, a1);
            }
            int ow = 9 * m + S - 1;
            float* yp = out + ((size_t)(n * 2) * 400 + oh) * 540 + ow;
            yp[0] = a0 + b0;
            yp[400 * 540] = a1 + b1;
        }
    }
}

// finalize
__global__ __launch_bounds__(512) void fin_k(const float* __restrict__ counts,
                                             const float* __restrict__ loss_sum,
                                             float* __restrict__ out, int out_size)
{
    __shared__ float red[512];
    int t = threadIdx.x;
    float c = counts[t];
    float p = c * (1.0f / 960.0f);
    red[t] = p * logf(p + 1e-10f);
    __syncthreads();
    for (int s = 256; s > 0; s >>= 1) {
        if (t < s) red[t] += red[t + s];
        __syncthreads();
    }
    if (t == 0) {
        out[out_size - 1] = expf(-red[0]);
        out[0] = loss_sum[0] * 1.25f / 61440.0f;
    }
}

extern "C" void kernel_launch(void* const* d_in, const int* in_sizes, int n_in,
                              void* d_out, int out_size, void* d_ws, size_t ws_size,
                              hipStream_t stream)
{
    const float* x          = (const float*)d_in[0];
    const float* enc_w1     = (const float*)d_in[1];
    const float* enc_b1     = (const float*)d_in[2];
    const float* enc_w2     = (const float*)d_in[3];
    const float* enc_b2     = (const float*)d_in[4];
    const float* enc_w3     = (const float*)d_in[5];
    const float* enc_b3     = (const float*)d_in[6];
    const float* enc_res_w1 = (const float*)d_in[7];
    const float* enc_res_w2 = (const float*)d_in[8];
    const float* pre_w      = (const float*)d_in[9];
    const float* pre_b      = (const float*)d_in[10];
    const float* emb        = (const float*)d_in[11];
    const float* dec_w1     = (const float*)d_in[12];
    const float* dec_b1     = (const float*)d_in[13];
    const float* dec_res_w1 = (const float*)d_in[14];
    const float* dec_res_w2 = (const float*)d_in[15];
    const float* dec_tw1    = (const float*)d_in[16];
    const float* dec_tb1    = (const float*)d_in[17];
    const float* dec_tw2    = (const float*)d_in[18];
    const float* dec_tb2    = (const float*)d_in[19];

    float* ws  = (float*)d_ws;
    float* out = (float*)d_out;

    float* h1       = ws;            // (32,64,50,66) = 6,758,400; later dmid_pad
    float* dmid     = ws;            // padded (32,64,52,62) = 6,602,752
    float* h2       = ws + 6758400;  // (32,128,5,6) = 122,880
    float* counts   = ws + 6881280;  // 512
    float* loss_sum = ws + 6881792;  // 1 (+pad to 64)
    float* wtA      = ws + 6881856;  // 1,179,648 (conv2 repack, then convt1 repack)
    float* wt2      = ws + 8061504;  // 14,080
    float* xpad     = ws + 8075584;  // 229,376
    float* wsm      = ws + 8304960;  // 557,056 -> end 8,862,016 floats (35.4 MB)

    hipMemsetAsync(counts, 0, 513 * sizeof(float), stream);

    // --- encoder ---
    repack_oihw_k<<<4608, 256, 0, stream>>>(enc_w2, wtA, 128, 64, 12, 12);
    conv1_k<<<1600, 256, 0, stream>>>(x, enc_w1, enc_b1, h1);
    conv2_k2<<<160, 512, 0, stream>>>(h1, wtA, enc_b2, h2);

    // --- fused 5x6 chain (enc3..VQ..dec res) ---
    repack_small_k<<<2176, 256, 0, stream>>>(enc_w3, enc_res_w1, enc_res_w2, pre_w,
                                             dec_w1, dec_res_w1, dec_res_w2, wsm);
    chain_k<<<32, 1024, 0, stream>>>(h2, wsm, enc_b3, pre_b, emb, dec_b1,
                                     xpad, counts, loss_sum);

    // --- decoder transposed convs ---
    repack_iohw_k<<<4608, 256, 0, stream>>>(dec_tw1, wtA, 128, 64, 12, 12);
    repack_iohw_k<<<55, 256, 0, stream>>>(dec_tw2, wt2, 64, 2, 10, 11);
    hipMemsetAsync(dmid, 0, (size_t)6602752 * sizeof(float), stream);
    convt1_k3<<<1600, 256, 0, stream>>>(xpad, wtA, dec_tb1, dmid);
    convt2_k3<<<1632, 256, 0, stream>>>(dmid, wt2, dec_tb2, out + 1);

    fin_k<<<1, 512, 0, stream>>>(counts, loss_sum, out, out_size);
}

// Round 8
// 2177.072 us; speedup vs baseline: 1.8140x; 1.0332x over previous
//
#include <hip/hip_runtime.h>
#include <math.h>

// ---------------------------------------------------------------------------
// VQ-VAE forward. Round 8: chain_k v3 — register-stationary K-split.
// r7 counters showed chain_k (1110us, VALUBusy 4%) is LDS-read-issue bound:
// ~0.8 FMA per LDS read. v3: acc[oc][30px] in registers, x reads broadcast
// once per channel (9-18 FMA/read), weights direct from global (coalesced),
// cross-wave reduction via ds_add into stride-61 LDS buffers.
// ---------------------------------------------------------------------------

// conv1: x(32,2,400,600) w(64,2,10,11) s(8,9) p(1,1) -> y(32,64,50,66), +b, relu
__global__ __launch_bounds__(256) void conv1_k(const float* __restrict__ x,
                                               const float* __restrict__ w,
                                               const float* __restrict__ b,
                                               float* __restrict__ y)
{
    __shared__ float xs[2 * 10 * 596]; // 47.68 KB
    const int blk = blockIdx.x;            // 32*50 = 1600
    const int n = blk / 50, oh = blk % 50;
    const int tid = threadIdx.x;
    const int ih0 = oh * 8 - 1;
    for (int i = tid; i < 2 * 10 * 596; i += 256) {
        int c = i / 5960, rem = i % 5960;
        int r = rem / 596, j = rem % 596;
        int ih = ih0 + r, iw = j - 1;
        float v = 0.f;
        if (ih >= 0 && ih < 400 && iw >= 0 && iw < 600)
            v = x[((n * 2 + c) * 400 + ih) * 600 + iw];
        xs[i] = v;
    }
    __syncthreads();
    for (int i = tid; i < 32 * 66; i += 256) {
        int oc = i / 66, ow = i % 66;
        int col = ow * 9;
        float a0 = 0.f, a1 = 0.f;
        for (int c = 0; c < 2; ++c) {
            const float* wp0 = w + ((oc)      * 2 + c) * 110;
            const float* wp1 = w + ((oc + 32) * 2 + c) * 110;
            const float* xp  = xs + c * 5960 + col;
            for (int kh = 0; kh < 10; ++kh) {
                #pragma unroll
                for (int kw = 0; kw < 11; ++kw) {
                    float xv = xp[kh * 596 + kw];
                    a0 += xv * wp0[kh * 11 + kw];
                    a1 += xv * wp1[kh * 11 + kw];
                }
            }
        }
        y[((n * 64 + oc)      * 50 + oh) * 66 + ow] = fmaxf(a0 + b[oc], 0.f);
        y[((n * 64 + oc + 32) * 50 + oh) * 66 + ow] = fmaxf(a1 + b[oc + 32], 0.f);
    }
}

// repack OIHW -> [c][kh][kw][oc]
__global__ __launch_bounds__(256) void repack_oihw_k(const float* __restrict__ w,
                                                     float* __restrict__ wt,
                                                     int OC, int IC, int KH, int KW)
{
    int i = blockIdx.x * 256 + threadIdx.x;
    int total = OC * IC * KH * KW;
    if (i >= total) return;
    int oc = i % OC; int t = i / OC;
    int kw = t % KW; int kh = (t / KW) % KH; int c = t / (KW * KH);
    wt[i] = w[((oc * IC + c) * KH + kh) * KW + kw];
}

// repack IOHW (transposed-conv weights) -> [c][kh][kw][oc]
__global__ __launch_bounds__(256) void repack_iohw_k(const float* __restrict__ w,
                                                     float* __restrict__ wt,
                                                     int IC, int OC, int KH, int KW)
{
    int i = blockIdx.x * 256 + threadIdx.x;
    int total = OC * IC * KH * KW;
    if (i >= total) return;
    int oc = i % OC; int t = i / OC;
    int kw = t % KW; int kh = (t / KW) % KH; int c = t / (KW * KH);
    wt[i] = w[((c * OC + oc) * KH + kh) * KW + kw];
}

__device__ __forceinline__ float fetch_oihw(const float* __restrict__ w, int j,
                                            int OC, int IC, int KH, int KW)
{
    int oc = j % OC; int t = j / OC;
    int kw = t % KW; int kh = (t / KW) % KH; int c = t / (KW * KH);
    return w[((oc * IC + c) * KH + kh) * KW + kw];
}

// all small-conv weights -> [c][kh][kw][oc], packed into one buffer
__global__ __launch_bounds__(256) void repack_small_k(
    const float* __restrict__ enc_w3, const float* __restrict__ er1,
    const float* __restrict__ er2, const float* __restrict__ pre_w,
    const float* __restrict__ dec_w1, const float* __restrict__ dr1,
    const float* __restrict__ dr2, float* __restrict__ dst)
{
    int i = blockIdx.x * 256 + threadIdx.x;
    if (i >= 557056) return;
    float v;
    if (i < 147456)       v = fetch_oihw(enc_w3,        i,          128, 128, 3, 3);
    else if (i < 221184)  v = fetch_oihw(er1,           i - 147456,  64, 128, 3, 3);
    else if (i < 294912)  v = fetch_oihw(er1 + 73728,   i - 221184,  64, 128, 3, 3);
    else if (i < 303104)  v = fetch_oihw(er2,           i - 294912, 128,  64, 1, 1);
    else if (i < 311296)  v = fetch_oihw(er2 + 8192,    i - 303104, 128,  64, 1, 1);
    else if (i < 319488)  v = fetch_oihw(pre_w,         i - 311296,  64, 128, 1, 1);
    else if (i < 393216)  v = fetch_oihw(dec_w1,        i - 319488, 128,  64, 3, 3);
    else if (i < 466944)  v = fetch_oihw(dr1,           i - 393216,  64, 128, 3, 3);
    else if (i < 540672)  v = fetch_oihw(dr1 + 73728,   i - 466944,  64, 128, 3, 3);
    else if (i < 548864)  v = fetch_oihw(dr2,           i - 540672, 128,  64, 1, 1);
    else                  v = fetch_oihw(dr2 + 8192,    i - 548864, 128,  64, 1, 1);
    dst[i] = v;
}

// conv2: h1(32,64,50,66) wt[c64][kh12][kw12][oc128] s10 p1 -> y(32,128,5,6), +b, relu
__global__ __launch_bounds__(512) void conv2_k2(const float* __restrict__ x,
                                                const float* __restrict__ wt,
                                                const float* __restrict__ b,
                                                float* __restrict__ y)
{
    __shared__ float xs[16 * 12 * 64];   // 49.2 KB
    __shared__ float sred[4 * 128 * 6];  // 12.3 KB
    const int tid = threadIdx.x;
    const int oc = tid & 127, sub = tid >> 7;  // sub = kh triplet
    const int n = blockIdx.x / 5, oh = blockIdx.x % 5;
    const int ih0 = oh * 10 - 1;
    float acc[6] = {0, 0, 0, 0, 0, 0};
    for (int cc = 0; cc < 4; ++cc) {
        __syncthreads();
        for (int i = tid; i < 12288; i += 512) {
            int col = i & 63; int t2 = i >> 6;
            int r = t2 % 12; int c = t2 / 12;
            int ih = ih0 + r, iw = col - 1;
            float v = 0.f;
            if (ih >= 0 && ih < 50 && iw >= 0 && iw < 66)
                v = x[((n * 64 + cc * 16 + c) * 50 + ih) * 66 + iw];
            xs[i] = v;
        }
        __syncthreads();
        for (int c = 0; c < 16; ++c) {
            for (int kh = sub * 3; kh < sub * 3 + 3; ++kh) {
                float xr[64];
                #pragma unroll
                for (int k = 0; k < 16; ++k)
                    *(float4*)&xr[4 * k] = *(const float4*)&xs[(c * 12 + kh) * 64 + 4 * k];
                const float* wp = wt + ((cc * 16 + c) * 144 + kh * 12) * 128 + oc;
                #pragma unroll
                for (int kw = 0; kw < 12; ++kw) {
                    float wv = wp[kw * 128];
                    #pragma unroll
                    for (int ow = 0; ow < 6; ++ow)
                        acc[ow] += xr[ow * 10 + kw] * wv;
                }
            }
        }
    }
    for (int j = 0; j < 6; ++j) sred[(sub * 128 + oc) * 6 + j] = acc[j];
    __syncthreads();
    if (sub == 0) {
        float bias = b[oc];
        #pragma unroll
        for (int j = 0; j < 6; ++j) {
            float v = acc[j] + sred[(128 + oc) * 6 + j] + sred[(256 + oc) * 6 + j]
                    + sred[(384 + oc) * 6 + j] + bias;
            y[((n * 128 + oc) * 5 + oh) * 6 + j] = fmaxf(v, 0.f);
        }
    }
}

// ---------------- fused 5x6 chain v3 ----------------
// thread = (slot = tid&63, g = tid>>6). OCPT = COUT/64 output channels per
// thread (oc = slot [+64]); acc[OCPT][30] in registers; K split over 16 waves.
// x reads: wave-uniform LDS broadcasts. weights: lane-coalesced global reads
// from repacked [c][kh][kw][oc]. Reduction: Q (waves 0-7) / P (waves 8-15)
// via ds_add, stride-61 rows (odd -> conflict-free), wave 0 combines.

template<int CIN, int COUT, int KS, bool RELU_IN, bool ACCUM, bool HASBIAS>
__device__ __forceinline__ void stagef(const float* __restrict__ src,
                                       const float* __restrict__ wg,
                                       const float* __restrict__ bias,
                                       float* __restrict__ dst,
                                       float* __restrict__ P,
                                       float* __restrict__ Q,
                                       int slot, int g)
{
    constexpr int OCPT = COUT / 64;      // 1 or 2
    constexpr int CPT  = CIN / 16;       // channels per wave-group
    constexpr int NV   = 30 * OCPT;
    constexpr int STR  = NV + 1;         // odd stride -> no bank conflicts
    float acc[OCPT][30];
    #pragma unroll
    for (int o = 0; o < OCPT; ++o)
        #pragma unroll
        for (int j = 0; j < 30; ++j) acc[o][j] = 0.f;

    const int c0 = g * CPT;
    for (int cc = 0; cc < CPT; ++cc) {
        const int c = c0 + cc;
        const float* sc = src + c * 30;
        if (KS == 3) {
            const float* wp = wg + c * 9 * COUT + slot;
            float w[OCPT][9];
            #pragma unroll
            for (int t = 0; t < 9; ++t)
                #pragma unroll
                for (int o = 0; o < OCPT; ++o) w[o][t] = wp[t * COUT + o * 64];
            #pragma unroll
            for (int rho = 0; rho < 5; ++rho) {
                float xr[6];
                #pragma unroll
                for (int q2 = 0; q2 < 6; ++q2) {
                    float xv = sc[rho * 6 + q2];
                    xr[q2] = RELU_IN ? fmaxf(xv, 0.f) : xv;
                }
                #pragma unroll
                for (int kh = 0; kh < 3; ++kh) {
                    const int r = rho + 1 - kh;   // output row fed by x-row rho
                    if (r < 0 || r > 4) continue;
                    #pragma unroll
                    for (int kw = 0; kw < 3; ++kw) {
                        #pragma unroll
                        for (int pc = 0; pc < 6; ++pc) {
                            const int gam = pc + kw - 1;  // x col
                            if (gam < 0 || gam > 5) continue;
                            #pragma unroll
                            for (int o = 0; o < OCPT; ++o)
                                acc[o][r * 6 + pc] += xr[gam] * w[o][kh * 3 + kw];
                        }
                    }
                }
            }
        } else {
            float w[OCPT];
            #pragma unroll
            for (int o = 0; o < OCPT; ++o) w[o] = wg[c * COUT + slot + o * 64];
            #pragma unroll
            for (int j = 0; j < 30; ++j) {
                float xv = sc[j];
                if (RELU_IN) xv = fmaxf(xv, 0.f);
                #pragma unroll
                for (int o = 0; o < OCPT; ++o) acc[o][j] += xv * w[o];
            }
        }
    }
    float* buf = (g < 8) ? Q : P;
    if (g == 0 || g == 8) {
        #pragma unroll
        for (int o = 0; o < OCPT; ++o)
            #pragma unroll
            for (int j = 0; j < 30; ++j) buf[slot * STR + o * 30 + j] = acc[o][j];
    }
    __syncthreads();
    if (g != 0 && g != 8) {
        #pragma unroll
        for (int o = 0; o < OCPT; ++o)
            #pragma unroll
            for (int j = 0; j < 30; ++j)
                atomicAdd(&buf[slot * STR + o * 30 + j], acc[o][j]);
    }
    __syncthreads();
    if (g == 0) {
        #pragma unroll
        for (int o = 0; o < OCPT; ++o) {
            const int oc = slot + o * 64;
            float bv = HASBIAS ? bias[oc] : 0.f;
            #pragma unroll
            for (int j = 0; j < 30; ++j) {
                float v = Q[slot * STR + o * 30 + j] + P[slot * STR + o * 30 + j] + bv;
                if (ACCUM) dst[oc * 30 + j] += v;
                else       dst[oc * 30 + j] = v;
            }
        }
    }
    __syncthreads();
}

// chain: h2 -> enc3 -> resx2 -> pre -> VQ -> dec1 -> resx2 -> relu+pad -> xpad
__global__ __launch_bounds__(1024) void chain_k(
    const float* __restrict__ h2, const float* __restrict__ wsm,
    const float* __restrict__ enc_b3, const float* __restrict__ pre_b,
    const float* __restrict__ emb, const float* __restrict__ dec_b1,
    float* __restrict__ xpad, float* __restrict__ counts,
    float* __restrict__ loss_sum)
{
    __shared__ float A[3840], B[3840], T[1920], Z[1920];
    __shared__ float P[64 * 61], Q[64 * 61];   // reduction buffers (30.5 KB)
    const int n = blockIdx.x;
    const int tid = threadIdx.x;
    const int slot = tid & 63, g = tid >> 6;
    for (int i = tid; i < 3840; i += 1024) A[i] = h2[n * 3840 + i];
    __syncthreads();
    // enc3: conv3x3 128->128 +b (input already relu'd by conv2)
    stagef<128, 128, 3, false, false, true>(A, wsm, enc_b3, B, P, Q, slot, g);
    // enc res0: conv3x3(relu) 128->64 ; conv1x1(relu) 64->128 accum
    stagef<128, 64, 3, true, false, false>(B, wsm + 147456, nullptr, T, P, Q, slot, g);
    stagef<64, 128, 1, true, true, false>(T, wsm + 294912, nullptr, B, P, Q, slot, g);
    // enc res1
    stagef<128, 64, 3, true, false, false>(B, wsm + 221184, nullptr, T, P, Q, slot, g);
    stagef<64, 128, 1, true, true, false>(T, wsm + 303104, nullptr, B, P, Q, slot, g);
    // pre: conv1x1(relu) 128->64 +b -> z
    stagef<128, 64, 1, true, false, true>(B, wsm + 311296, pre_b, Z, P, Q, slot, g);
    // --- VQ: wave per pixel (identical math/order to validated version) ---
    for (int px = g; px < 30; px += 16) {
        float zr[64];
        #pragma unroll
        for (int d = 0; d < 64; ++d) zr[d] = Z[d * 30 + px];
        float best = 1e30f; int bestk = 0;
        for (int jk = 0; jk < 8; ++jk) {
            int k = slot + jk * 64;
            const float* ep = emb + k * 64;
            float dist = 0.f;
            #pragma unroll 8
            for (int d = 0; d < 64; ++d) { float df = ep[d] - zr[d]; dist += df * df; }
            if (dist < best) { best = dist; bestk = k; }
        }
        for (int off = 32; off; off >>= 1) {
            float ob = __shfl_down(best, off); int ok = __shfl_down(bestk, off);
            if (ob < best || (ob == best && ok < bestk)) { best = ob; bestk = ok; }
        }
        bestk = __shfl(bestk, 0);
        float ev = emb[bestk * 64 + slot];
        T[slot * 30 + px] = ev;                       // q
        float df = ev - Z[slot * 30 + px]; df *= df;
        for (int off = 32; off; off >>= 1) df += __shfl_down(df, off);
        if (slot == 0) { atomicAdd(loss_sum, df); atomicAdd(&counts[bestk], 1.f); }
    }
    __syncthreads();
    // dec1: conv3x3 64->128 +b (input q, no relu)
    stagef<64, 128, 3, false, false, true>(T, wsm + 319488, dec_b1, A, P, Q, slot, g);
    // dec res0
    stagef<128, 64, 3, true, false, false>(A, wsm + 393216, nullptr, T, P, Q, slot, g);
    stagef<64, 128, 1, true, true, false>(T, wsm + 540672, nullptr, A, P, Q, slot, g);
    // dec res1
    stagef<128, 64, 3, true, false, false>(A, wsm + 466944, nullptr, T, P, Q, slot, g);
    stagef<64, 128, 1, true, true, false>(T, wsm + 548864, nullptr, A, P, Q, slot, g);
    // final relu + zero-pad to xpad[n][128][7][8]
    for (int i = tid; i < 7168; i += 1024) {
        int col = i & 7, r = (i >> 3) % 7, c = i / 56;
        float v = 0.f;
        if (r >= 1 && r <= 5 && col >= 1 && col <= 6)
            v = fmaxf(A[c * 30 + (r - 1) * 6 + col - 1], 0.f);
        xpad[n * 7168 + i] = v;
    }
}

// ---------------- convt1 ----------------

template<bool TR, bool TS>
__device__ __forceinline__ void ct1_accum(const float* __restrict__ xs0,
                                          const float* __restrict__ xs1,
                                          const float* __restrict__ wt,
                                          int R, int S, int m0, int lane,
                                          float acc[6])
{
    #pragma unroll 2
    for (int c = 0; c < 128; ++c) {
        float x1[7], x0[7];
        #pragma unroll
        for (int k = 0; k < 7; ++k) x1[k] = xs1[c * 8 + m0 + k];
        if (TR) {
            #pragma unroll
            for (int k = 0; k < 7; ++k) x0[k] = xs0[c * 8 + m0 + k];
        }
        float wA = wt[(c * 144 + R * 12 + S) * 64 + lane];
        #pragma unroll
        for (int j = 0; j < 6; ++j) acc[j] += x1[j + 1] * wA;
        if (TS) {
            float wB = wt[(c * 144 + R * 12 + S + 10) * 64 + lane];
            #pragma unroll
            for (int j = 0; j < 6; ++j) acc[j] += x1[j] * wB;
        }
        if (TR) {
            float wC = wt[(c * 144 + (R + 10) * 12 + S) * 64 + lane];
            #pragma unroll
            for (int j = 0; j < 6; ++j) acc[j] += x0[j + 1] * wC;
            if (TS) {
                float wD = wt[(c * 144 + (R + 10) * 12 + S + 10) * 64 + lane];
                #pragma unroll
                for (int j = 0; j < 6; ++j) acc[j] += x0[j] * wD;
            }
        }
    }
}

// convt1: xpad(32,128,7,8) wt[c128][12][12][oc64] s10 p1 -> dmid_pad[32][64][52][62]
__global__ __launch_bounds__(256) void convt1_k3(const float* __restrict__ xp,
                                                 const float* __restrict__ wt,
                                                 const float* __restrict__ b,
                                                 float* __restrict__ y)
{
    __shared__ float xs[2][128][8];   // 8 KB
    const int bi = blockIdx.x;        // 32*50
    const int n = bi / 50, oh = bi % 50;
    const int q = (oh + 1) / 10, R = (oh + 1) % 10;
    const int tid = threadIdx.x;
    for (int i = tid; i < 2048; i += 256) {
        int col = i & 7, c = (i >> 3) & 127, r = i >> 10;
        ((float*)xs)[i] = xp[((n * 128 + c) * 7 + q + r) * 8 + col];
    }
    __syncthreads();
    const int lane = tid & 63, wv = tid >> 6;
    const float bias = b[lane];
    const float* xs0 = &xs[0][0][0];
    const float* xs1 = &xs[1][0][0];
    for (int si = 0; si < 3; ++si) {
        int S = wv + si * 4;
        if (S >= 10) break;
        int m0 = (S == 0) ? 1 : 0;
        float acc[6] = {0, 0, 0, 0, 0, 0};
        if (R < 2) {
            if (S < 2) ct1_accum<true, true>(xs0, xs1, wt, R, S, m0, lane, acc);
            else       ct1_accum<true, false>(xs0, xs1, wt, R, S, m0, lane, acc);
        } else {
            if (S < 2) ct1_accum<false, true>(xs0, xs1, wt, R, S, m0, lane, acc);
            else       ct1_accum<false, false>(xs0, xs1, wt, R, S, m0, lane, acc);
        }
        float* yp = y + ((n * 64 + lane) * 52 + oh + 1) * 62 + 10 * m0 + S;
        #pragma unroll
        for (int j = 0; j < 6; ++j) yp[10 * j] = fmaxf(acc[j] + bias, 0.f);
    }
}

// ---------------- convt2 ----------------

template<bool TR, bool TS>
__device__ __forceinline__ void ct2_accum(const float* __restrict__ xs0,
                                          const float* __restrict__ xs1,
                                          const float* __restrict__ wt2,
                                          int R, int S, int m,
                                          float& a0, float& a1)
{
    #pragma unroll 4
    for (int c = 0; c < 64; ++c) {
        float x1a = xs1[c * 64 + m + 1];
        float2 wA = *(const float2*)&wt2[(c * 110 + R * 11 + S) * 2];
        a0 += x1a * wA.x; a1 += x1a * wA.y;
        if (TS) {
            float x1b = xs1[c * 64 + m];
            float2 wB = *(const float2*)&wt2[(c * 110 + R * 11 + S + 9) * 2];
            a0 += x1b * wB.x; a1 += x1b * wB.y;
        }
        if (TR) {
            float x0a = xs0[c * 64 + m + 1];
            float2 wC = *(const float2*)&wt2[(c * 110 + (R + 8) * 11 + S) * 2];
            a0 += x0a * wC.x; a1 += x0a * wC.y;
            if (TS) {
                float x0b = xs0[c * 64 + m];
                float2 wD = *(const float2*)&wt2[(c * 110 + (R + 8) * 11 + S + 9) * 2];
                a0 += x0b * wD.x; a1 += x0b * wD.y;
            }
        }
    }
}

// convt2: dmid_pad[32][64][52][62] wt2[c64][10][11][oc2] s(8,9) p1 -> out(32,2,400,540)+b
__global__ __launch_bounds__(256) void convt2_k3(const float* __restrict__ xd,
                                                 const float* __restrict__ wt2,
                                                 const float* __restrict__ bb,
                                                 float* __restrict__ out)
{
    __shared__ float xs[2][64][64];   // 32 KB
    const int bi = blockIdx.x;        // 32*51
    const int n = bi / 51, io = bi % 51;
    const int tid = threadIdx.x;
    for (int i = tid; i < 2 * 64 * 64; i += 256) {
        int col = i & 63, c = (i >> 6) & 63, r = i >> 12;
        float v = 0.f;
        if (col < 62) v = xd[((n * 64 + c) * 52 + io + r) * 62 + col];
        ((float*)xs)[i] = v;
    }
    __syncthreads();
    const float b0 = bb[0], b1 = bb[1];
    const int lane = tid & 63, wv = tid >> 6;
    if (lane < 60) {
        const float* xs0 = &xs[0][0][0];
        const float* xs1 = &xs[1][0][0];
        for (int pp = 0; pp < 18; ++pp) {
            int p = wv * 18 + pp;
            int R = p / 9, S = p % 9;
            int oh = 8 * io + R - 1;
            if (oh < 0 || oh >= 400) continue;
            int m = lane + ((S == 0) ? 1 : 0);
            float a0 = 0.f, a1 = 0.f;
            if (R < 2) {
                if (S < 2) ct2_accum<true, true>(xs0, xs1, wt2, R, S, m, a0, a1);
                else       ct2_accum<true, false>(xs0, xs1, wt2, R, S, m, a0, a1);
            } else {
                if (S < 2) ct2_accum<false, true>(xs0, xs1, wt2, R, S, m, a0, a1);
                else       ct2_accum<false, false>(xs0, xs1, wt2, R, S, m, a0, a1);
            }
            int ow = 9 * m + S - 1;
            float* yp = out + ((size_t)(n * 2) * 400 + oh) * 540 + ow;
            yp[0] = a0 + b0;
            yp[400 * 540] = a1 + b1;
        }
    }
}

// finalize
__global__ __launch_bounds__(512) void fin_k(const float* __restrict__ counts,
                                             const float* __restrict__ loss_sum,
                                             float* __restrict__ out, int out_size)
{
    __shared__ float red[512];
    int t = threadIdx.x;
    float c = counts[t];
    float p = c * (1.0f / 960.0f);
    red[t] = p * logf(p + 1e-10f);
    __syncthreads();
    for (int s = 256; s > 0; s >>= 1) {
        if (t < s) red[t] += red[t + s];
        __syncthreads();
    }
    if (t == 0) {
        out[out_size - 1] = expf(-red[0]);
        out[0] = loss_sum[0] * 1.25f / 61440.0f;
    }
}

extern "C" void kernel_launch(void* const* d_in, const int* in_sizes, int n_in,
                              void* d_out, int out_size, void* d_ws, size_t ws_size,
                              hipStream_t stream)
{
    const float* x          = (const float*)d_in[0];
    const float* enc_w1     = (const float*)d_in[1];
    const float* enc_b1     = (const float*)d_in[2];
    const float* enc_w2     = (const float*)d_in[3];
    const float* enc_b2     = (const float*)d_in[4];
    const float* enc_w3     = (const float*)d_in[5];
    const float* enc_b3     = (const float*)d_in[6];
    const float* enc_res_w1 = (const float*)d_in[7];
    const float* enc_res_w2 = (const float*)d_in[8];
    const float* pre_w      = (const float*)d_in[9];
    const float* pre_b      = (const float*)d_in[10];
    const float* emb        = (const float*)d_in[11];
    const float* dec_w1     = (const float*)d_in[12];
    const float* dec_b1     = (const float*)d_in[13];
    const float* dec_res_w1 = (const float*)d_in[14];
    const float* dec_res_w2 = (const float*)d_in[15];
    const float* dec_tw1    = (const float*)d_in[16];
    const float* dec_tb1    = (const float*)d_in[17];
    const float* dec_tw2    = (const float*)d_in[18];
    const float* dec_tb2    = (const float*)d_in[19];

    float* ws  = (float*)d_ws;
    float* out = (float*)d_out;

    float* h1       = ws;            // (32,64,50,66) = 6,758,400; later dmid_pad
    float* dmid     = ws;            // padded (32,64,52,62) = 6,602,752
    float* h2       = ws + 6758400;  // (32,128,5,6) = 122,880
    float* counts   = ws + 6881280;  // 512
    float* loss_sum = ws + 6881792;  // 1 (+pad to 64)
    float* wtA      = ws + 6881856;  // 1,179,648 (conv2 repack, then convt1 repack)
    float* wt2      = ws + 8061504;  // 14,080
    float* xpad     = ws + 8075584;  // 229,376
    float* wsm      = ws + 8304960;  // 557,056 -> end 8,862,016 floats (35.4 MB)

    hipMemsetAsync(counts, 0, 513 * sizeof(float), stream);

    // --- encoder ---
    repack_oihw_k<<<4608, 256, 0, stream>>>(enc_w2, wtA, 128, 64, 12, 12);
    conv1_k<<<1600, 256, 0, stream>>>(x, enc_w1, enc_b1, h1);
    conv2_k2<<<160, 512, 0, stream>>>(h1, wtA, enc_b2, h2);

    // --- fused 5x6 chain (enc3..VQ..dec res) ---
    repack_small_k<<<2176, 256, 0, stream>>>(enc_w3, enc_res_w1, enc_res_w2, pre_w,
                                             dec_w1, dec_res_w1, dec_res_w2, wsm);
    chain_k<<<32, 1024, 0, stream>>>(h2, wsm, enc_b3, pre_b, emb, dec_b1,
                                     xpad, counts, loss_sum);

    // --- decoder transposed convs ---
    repack_iohw_k<<<4608, 256, 0, stream>>>(dec_tw1, wtA, 128, 64, 12, 12);
    repack_iohw_k<<<55, 256, 0, stream>>>(dec_tw2, wt2, 64, 2, 10, 11);
    hipMemsetAsync(dmid, 0, (size_t)6602752 * sizeof(float), stream);
    convt1_k3<<<1600, 256, 0, stream>>>(xpad, wtA, dec_tb1, dmid);
    convt2_k3<<<1632, 256, 0, stream>>>(dmid, wt2, dec_tb2, out + 1);

    fin_k<<<1, 512, 0, stream>>>(counts, loss_sum, out, out_size);
}